// Round 14
// baseline (287.914 us; speedup 1.0000x reference)
//
#include <hip/hip_runtime.h>

#define BB 2
#define NN 16384
#define CC 64
#define SS 4096
#define KK 32
#define R2 0.16f   // RADIUS^2

// spatial grid: cell = RADIUS, 24^3 cells covering [-4.8, 4.8] (clamped; the
// clamp is monotone so the 3x3x3 neighborhood remains a superset of the ball
// for ANY input magnitude — tail points just pile into edge cells)
#define GD   24
#define GC   (GD * GD * GD)       // 13824 cells per batch
#define CAPC 112                  // per-cell point bucket capacity (center ~66)
#define CCAP 64                   // per-cell CENTROID bucket capacity (lam~17)
#define CAP  512                  // per-wave hit-list capacity
#define CAPL (CAP / 64)           // 8 register chunks for selection
#define CANDN 1536                // per-block LDS candidate capacity (E_max~1500)

typedef __bf16 bf16x8 __attribute__((ext_vector_type(8)));
typedef float  f32x4  __attribute__((ext_vector_type(4)));

#define MFMA(a, b, c) __builtin_amdgcn_mfma_f32_16x16x32_bf16((a), (b), (c), 0, 0, 0)

static __device__ __forceinline__ ushort f2bf(float f) {
    __bf16 h = (__bf16)f;
    return *(ushort*)&h;
}

static __device__ __forceinline__ int cellc(float x) {
    int i = (int)floorf(x * 2.5f + 12.0f);
    return i < 0 ? 0 : (i > GD - 1 ? GD - 1 : i);
}

// workspace section offsets (bytes), all 16B aligned
#define WS_PTS4   0          // pts4:    2*16384*16    =   524,288
#define WS_FEAT   524288     // feat_nc: 2*16384*64*2  = 4,194,304
#define WS_W1T    4718592    // 64*96*2   = 12,288
#define WS_W2T    4730880    // 64*64*2   =  8,192
#define WS_W3T    4739072    // 128*64*2  = 16,384
#define WS_CNT    4755456    // counts: 2*13824*4 = 110,592
#define WS_CCNT   4866048    // centroid counts: 110,592
#define WS_WLC    4976640    // worklist cursor: 16
#define WS_WL     4976656    // worklist: 8192*4 = 32,768
#define WS_LPTS   5009424    // coord+id buckets: 2*13824*112*16 = 49,545,216
#define WS_CSLOT  54554640   // centroid slots: 2*13824*64*4 = 7,077,888
                             // (end 61,632,528)
#define MEMSET_B  221200     // counts + ccnt + cursor, contiguous

// prep index ranges (block-granular: T_SIDX = 328 blocks exactly)
#define T_PTS   (BB * NN)                  // 32768
#define T_W1    (T_PTS + 64 * 96)          // 38912
#define T_W2    (T_W1 + 64 * 64)           // 43008
#define T_W3    (T_W2 + 128 * 64)          // 51200
#define T_NXYZ  (T_W3 + BB * SS * 3)       // 75776
#define T_SIDX  (T_NXYZ + BB * SS)         // 83968 = 328*256
#define FEAT_B0 (T_SIDX / 256)             // 328: first feat-transpose block
#define NBLK    (FEAT_B0 + BB * (NN / 32)) // 1352 blocks

// ---------------------------------------------------------------------------
// prep: pts4 + point bucket insert + CENTROID bucket insert + worklist of
// occupied (b,cell) pairs; bf16 weight transposes; new_xyz copy; samp_idx;
// feat transpose via LDS tiles. One wide launch.
// ---------------------------------------------------------------------------
__global__ __launch_bounds__(256) void prep_kernel(
        const float* __restrict__ xyz, const float* __restrict__ feat,
        const float* __restrict__ W1, const float* __restrict__ W2,
        const float* __restrict__ W3,
        float4* __restrict__ pts4, ushort* __restrict__ feat_nc,
        ushort* __restrict__ W1t, ushort* __restrict__ W2t,
        ushort* __restrict__ W3t,
        float* __restrict__ out_xyz, float* __restrict__ out_sidx,
        uint* __restrict__ counts, float4* __restrict__ lpts,
        uint* __restrict__ ccnt, int* __restrict__ cslot,
        uint* __restrict__ wlc, uint* __restrict__ wl) {
    if (blockIdx.x >= FEAT_B0) {
        // ---- LDS-tiled feat transpose: one 64ch x 32pt tile per block ----
        __shared__ float tile[64][33];                 // +1 pad
        const int g = blockIdx.x - FEAT_B0;            // 0..1023
        const int b = g >> 9, n0 = (g & 511) << 5;
        const int t = threadIdx.x;
        const float* fb = feat + (size_t)b * CC * NN + n0;
        #pragma unroll
        for (int cc = 0; cc < 8; ++cc) {
            const int c = cc * 8 + (t >> 5);
            tile[c][t & 31] = fb[(size_t)c * NN + (t & 31)];
        }
        __syncthreads();
        const int p = t >> 3, c8 = t & 7;
        uint u[4];
        #pragma unroll
        for (int q = 0; q < 4; ++q) {
            u[q] = (uint)f2bf(tile[c8 * 8 + 2 * q][p]) |
                   ((uint)f2bf(tile[c8 * 8 + 2 * q + 1][p]) << 16);
        }
        *(uint4*)(feat_nc + ((size_t)b * NN + n0 + p) * 64 + c8 * 8) =
            make_uint4(u[0], u[1], u[2], u[3]);
        return;
    }
    const int t = blockIdx.x * 256 + threadIdx.x;
    if (t < T_PTS) {
        const float* p = xyz + (size_t)t * 3;
        const float x = p[0], y = p[1], z = p[2];
        pts4[t] = make_float4(x, y, z, x * x + y * y + z * z);
        const int cell = (cellc(z) * GD + cellc(y)) * GD + cellc(x);
        const int b = t >> 14, n = t & (NN - 1);
        const uint rank = atomicAdd(&counts[(size_t)b * GC + cell], 1u);
        if (rank < CAPC) {
            const size_t slot = ((size_t)b * GC + cell) * CAPC + rank;
            lpts[slot] = make_float4(x, y, z, __int_as_float(n));
        }
        if (n < SS) {                         // centroid: bin + worklist
            const uint rk = atomicAdd(&ccnt[(size_t)b * GC + cell], 1u);
            if (rk < CCAP) {
                cslot[((size_t)b * GC + cell) * CCAP + rk] = n;
                if (rk == 0) {
                    const uint wi = atomicAdd(wlc, 1u);
                    wl[wi] = ((uint)b << 16) | (uint)cell;
                }
            }
        }
    } else if (t < T_W1) {
        const int i = t - T_PTS;
        const int n = i / 96, k = i - n * 96;
        float v = 0.0f;
        if (k < 64) v = W1[(3 + k) * 64 + n];
        else if (k < 67) v = W1[(k - 64) * 64 + n];
        W1t[n * 96 + k] = f2bf(v);
    } else if (t < T_W2) {
        const int i = t - T_W1;
        const int n = i >> 6, k = i & 63;
        W2t[n * 64 + k] = f2bf(W2[k * 64 + n]);
    } else if (t < T_W3) {
        const int i = t - T_W2;
        const int n = i >> 6, k = i & 63;
        W3t[n * 64 + k] = f2bf(W3[k * 128 + n]);
    } else if (t < T_NXYZ) {
        const int i = t - T_W3;              // new_xyz = xyz[:, :SS] copy
        const int b = i / (SS * 3), j = i - b * (SS * 3);
        out_xyz[i] = xyz[(size_t)b * NN * 3 + j];
    } else if (t < T_SIDX) {
        const int i = t - T_NXYZ;
        out_sidx[i] = (float)(i & (SS - 1));
    }
}

// ---------------------------------------------------------------------------
// fused: one block iteration = one occupied (b,cell); the cell's 27-cell
// candidate neighborhood loads ONCE into LDS (4-wave split, coalesced), then
// each wave processes one of the cell's centroids against LDS-resident
// candidates — amortizing the L3 candidate traffic by centroids/cell (~16 in
// the dense cells where the time goes) and converting the candidate stream
// from L3 latency to ds_read_b128. Selection, gather, MLP: verbatim R13.
// Epilogue: direct per-centroid scatter (s arbitrary per wave).
// LDS: cand 24KB + 4x6656B gbuf = 51,200B -> 3 blocks/CU.
// ---------------------------------------------------------------------------
__global__ __launch_bounds__(256, 2) void fused_kernel(
        const float4* __restrict__ pts4, const ushort* __restrict__ feat_nc,
        const uint* __restrict__ counts, const float4* __restrict__ lpts,
        const uint* __restrict__ ccnt, const int* __restrict__ cslot,
        const uint* __restrict__ wlc, const uint* __restrict__ wl,
        const ushort* __restrict__ W1t, const ushort* __restrict__ W2t,
        const ushort* __restrict__ W3t,
        const float* __restrict__ b1, const float* __restrict__ b2,
        const float* __restrict__ b3, float* __restrict__ out_feat) {
    const int w = threadIdx.x >> 6, lane = threadIdx.x & 63;
    const int quad = lane >> 4, mrow = lane & 15;
    const int m = lane & 31, half = lane >> 5;

    __shared__ __align__(16) float4 cand[CANDN];         // 24,576 B
    __shared__ __align__(16) ushort ldsA[4][32 * 104];   // 26,624 B
    ushort* gbuf = ldsA[w];
    int* hit = (int*)gbuf;                               // first 2KB of gbuf
    const unsigned long long ltmask = (1ull << lane) - 1ull;

    const uint nwl = *wlc;
    for (uint wi = blockIdx.x; wi < nwl; wi += gridDim.x) {
        __syncthreads();                                 // protect cand reuse
        const uint wle = wl[wi];
        const int b = (int)(wle >> 16), cell = (int)(wle & 0xffffu);
        const int czc = cell / (GD * GD);
        const int rem = cell - czc * GD * GD;
        const int cyc = rem / GD, cxc = rem % GD;

        const float4* pb = pts4 + (size_t)b * NN;
        const ushort* fbase = feat_nc + (size_t)b * NN * 64;
        const uint* cntb = counts + (size_t)b * GC;
        const float4* lptsb = lpts + (size_t)b * GC * CAPC;

        // ---- 27-cell prefix (redundant per wave; cheap scalar loads) ----
        int pre[28], baseE[27];
        pre[0] = 0;
        #pragma unroll
        for (int e = 0; e < 27; ++e) {
            const int z = czc + e / 9 - 1;
            const int y = cyc + (e / 3) % 3 - 1;
            const int x = cxc + e % 3 - 1;
            const bool ok = ((unsigned)z < GD) && ((unsigned)y < GD) && ((unsigned)x < GD);
            const int ci = (z * GD + y) * GD + x;
            int cn = ok ? (int)cntb[ok ? ci : 0] : 0;
            cn = cn < CAPC ? cn : CAPC;
            if (cn > CANDN - pre[e]) cn = CANDN - pre[e];  // LDS cap clamp
            baseE[e] = ci * CAPC;
            pre[e + 1] = pre[e] + cn;
        }
        const int tot = pre[27];

        // ---- cooperative copy: wave w handles cells e % 4 == w ----
        for (int e = w; e < 27; e += 4) {
            const int cn = pre[e + 1] - pre[e];
            if (lane < cn) cand[pre[e] + lane] = lptsb[baseE[e] + lane];
            if (cn > 64 && lane + 64 < cn)
                cand[pre[e] + 64 + lane] = lptsb[baseE[e] + 64 + lane];
        }
        __syncthreads();

        // ---- per-wave centroid loop over this cell's centroids ----
        const uint ncr = ccnt[(size_t)b * GC + cell];
        const int nc = (int)(ncr < CCAP ? ncr : CCAP);
        for (int i = w; i < nc; i += 4) {
            const int s = cslot[((size_t)b * GC + cell) * CCAP + i];
            const float4 c = pb[s];

            int cnt = 0;
            for (int g0 = 0; g0 < tot; g0 += 64) {
                const int g = g0 + lane;
                const float4 pc = cand[g < tot ? g : 0];
                const bool act = g < tot;
                const float pw = pc.x * pc.x + pc.y * pc.y + pc.z * pc.z;
                const float d = c.w + pw - 2.0f * (c.x * pc.x + c.y * pc.y + c.z * pc.z);
                const bool h = act && (d < R2);
                const unsigned long long mk = __ballot(h);
                if (h) {
                    const int pp = cnt + __popcll(mk & ltmask);
                    if (pp < CAP) hit[pp] = __float_as_int(pc.w);
                }
                cnt += (int)__popcll(mk);
            }

            // ---- 32 smallest ids (set-equivalent to reference) ----
            if (cnt > KK) {
                const int stored = cnt < CAP ? cnt : CAP;
                int v[CAPL];
                #pragma unroll
                for (int j = 0; j < CAPL; ++j) {
                    if (j * 64 < stored) {
                        const int q = j * 64 + lane;
                        v[j] = (q < stored) ? hit[q] : 0x7fffffff;
                    } else {
                        v[j] = 0x7fffffff;
                    }
                }
                int lo = 0, hi = NN - 1;
                while (lo < hi) {
                    const int mid = (lo + hi) >> 1;
                    int cle = 0;
                    #pragma unroll
                    for (int j = 0; j < CAPL; ++j)
                        if (j * 64 < stored)
                            cle += (int)__popcll(__ballot(v[j] <= mid));
                    if (cle >= KK) hi = mid; else lo = mid + 1;
                }
                int pos = 0;
                #pragma unroll
                for (int j = 0; j < CAPL; ++j) {
                    if (j * 64 < stored) {
                        const bool sel = v[j] <= lo;
                        const unsigned long long mk = __ballot(sel);
                        if (sel) hit[pos + __popcll(mk & ltmask)] = v[j];
                        pos += (int)__popcll(mk);
                    }
                }
            } else if (lane < KK) {
                const int vv = (cnt == 0) ? 0 : ((lane < cnt) ? hit[lane] : hit[0]);
                hit[lane] = vv;
            }

            // ---- gather: sid (LDS) -> rows -> LDS ----
            {
                const int sid = hit[m];              // read before overwrite
                const ushort* src = fbase + (size_t)sid * 64 + half * 32;
                ushort* dst = gbuf + m * 104 + half * 32;
                uint4 rows[4];
                #pragma unroll
                for (int i2 = 0; i2 < 4; ++i2) rows[i2] = *(const uint4*)(src + i2 * 8);
                const float4 p = pb[sid];
                #pragma unroll
                for (int i2 = 0; i2 < 4; ++i2) *(uint4*)(dst + i2 * 8) = rows[i2];
                if (half == 0) {
                    bf16x8 rel = {(__bf16)(p.x - c.x), (__bf16)(p.y - c.y),
                                  (__bf16)(p.z - c.z), (__bf16)0.f,
                                  (__bf16)0.f, (__bf16)0.f, (__bf16)0.f, (__bf16)0.f};
                    *(bf16x8*)(gbuf + m * 104 + 64) = rel;
                    *(uint4*)(gbuf + m * 104 + 88) = make_uint4(0, 0, 0, 0);
                } else {
                    *(uint4*)(gbuf + m * 104 + 72) = make_uint4(0, 0, 0, 0);
                    *(uint4*)(gbuf + m * 104 + 80) = make_uint4(0, 0, 0, 0);
                }
            }

            // ---- layer 1: [32x96]x[96x64] ----
            {
                f32x4 acc[2][4];
                #pragma unroll
                for (int nt = 0; nt < 4; ++nt) {
                    const float bv = b1[nt * 16 + mrow];
                    acc[0][nt] = (f32x4){bv, bv, bv, bv};
                    acc[1][nt] = acc[0][nt];
                }
                #pragma unroll
                for (int ks = 0; ks < 3; ++ks) {
                    const bf16x8 a0 = *(const bf16x8*)(gbuf + mrow * 104 + ks * 32 + quad * 8);
                    const bf16x8 a1 = *(const bf16x8*)(gbuf + (16 + mrow) * 104 + ks * 32 + quad * 8);
                    #pragma unroll
                    for (int nt = 0; nt < 4; ++nt) {
                        const bf16x8 wf = *(const bf16x8*)(W1t + (nt * 16 + mrow) * 96 + ks * 32 + quad * 8);
                        acc[0][nt] = MFMA(a0, wf, acc[0][nt]);
                        acc[1][nt] = MFMA(a1, wf, acc[1][nt]);
                    }
                }
                #pragma unroll
                for (int mt = 0; mt < 2; ++mt)
                    #pragma unroll
                    for (int nt = 0; nt < 4; ++nt)
                        #pragma unroll
                        for (int r = 0; r < 4; ++r)
                            gbuf[(mt * 16 + quad * 4 + r) * 104 + nt * 16 + mrow] =
                                f2bf(fmaxf(acc[mt][nt][r], 0.0f));
            }

            // ---- layer 2: [32x64]x[64x64] ----
            {
                f32x4 acc[2][4];
                #pragma unroll
                for (int nt = 0; nt < 4; ++nt) {
                    const float bv = b2[nt * 16 + mrow];
                    acc[0][nt] = (f32x4){bv, bv, bv, bv};
                    acc[1][nt] = acc[0][nt];
                }
                #pragma unroll
                for (int ks = 0; ks < 2; ++ks) {
                    const bf16x8 a0 = *(const bf16x8*)(gbuf + mrow * 104 + ks * 32 + quad * 8);
                    const bf16x8 a1 = *(const bf16x8*)(gbuf + (16 + mrow) * 104 + ks * 32 + quad * 8);
                    #pragma unroll
                    for (int nt = 0; nt < 4; ++nt) {
                        const bf16x8 wf = *(const bf16x8*)(W2t + (nt * 16 + mrow) * 64 + ks * 32 + quad * 8);
                        acc[0][nt] = MFMA(a0, wf, acc[0][nt]);
                        acc[1][nt] = MFMA(a1, wf, acc[1][nt]);
                    }
                }
                #pragma unroll
                for (int mt = 0; mt < 2; ++mt)
                    #pragma unroll
                    for (int nt = 0; nt < 4; ++nt)
                        #pragma unroll
                        for (int r = 0; r < 4; ++r)
                            gbuf[(mt * 16 + quad * 4 + r) * 104 + nt * 16 + mrow] =
                                f2bf(fmaxf(acc[mt][nt][r], 0.0f));
            }

            // ---- layer 3: [32x64]x[64x128] two n-halves + maxpool ----
            #pragma unroll
            for (int nh = 0; nh < 2; ++nh) {
                f32x4 acc[2][4];
                #pragma unroll
                for (int ntl = 0; ntl < 4; ++ntl) {
                    const float bv = b3[(nh * 4 + ntl) * 16 + mrow];
                    acc[0][ntl] = (f32x4){bv, bv, bv, bv};
                    acc[1][ntl] = acc[0][ntl];
                }
                #pragma unroll
                for (int ks = 0; ks < 2; ++ks) {
                    const bf16x8 a0 = *(const bf16x8*)(gbuf + mrow * 104 + ks * 32 + quad * 8);
                    const bf16x8 a1 = *(const bf16x8*)(gbuf + (16 + mrow) * 104 + ks * 32 + quad * 8);
                    #pragma unroll
                    for (int ntl = 0; ntl < 4; ++ntl) {
                        const bf16x8 wf = *(const bf16x8*)(
                            W3t + ((nh * 4 + ntl) * 16 + mrow) * 64 + ks * 32 + quad * 8);
                        acc[0][ntl] = MFMA(a0, wf, acc[0][ntl]);
                        acc[1][ntl] = MFMA(a1, wf, acc[1][ntl]);
                    }
                }
                #pragma unroll
                for (int ntl = 0; ntl < 4; ++ntl) {
                    const f32x4 v0 = acc[0][ntl], v1 = acc[1][ntl];
                    float mx = fmaxf(fmaxf(v0[0], v0[1]), fmaxf(v0[2], v0[3]));
                    mx = fmaxf(mx, fmaxf(fmaxf(v1[0], v1[1]), fmaxf(v1[2], v1[3])));
                    mx = fmaxf(mx, __shfl_xor(mx, 16));
                    mx = fmaxf(mx, __shfl_xor(mx, 32));
                    mx = fmaxf(mx, 0.0f);
                    if (quad == 0) {           // direct scatter (s arbitrary)
                        const int ch = (nh * 4 + ntl) * 16 + mrow;
                        out_feat[((size_t)b * 128 + ch) * SS + s] = mx;
                    }
                }
            }
        }
    }
}

// ---------------------------------------------------------------------------
extern "C" void kernel_launch(void* const* d_in, const int* in_sizes, int n_in,
                              void* d_out, int out_size, void* d_ws, size_t ws_size,
                              hipStream_t stream) {
    const float* xyz  = (const float*)d_in[0];
    const float* feat = (const float*)d_in[1];
    const float* W1   = (const float*)d_in[2];
    const float* b1   = (const float*)d_in[3];
    const float* W2   = (const float*)d_in[4];
    const float* b2   = (const float*)d_in[5];
    const float* W3   = (const float*)d_in[6];
    const float* b3   = (const float*)d_in[7];

    float* out      = (float*)d_out;
    float* out_xyz  = out;                               // [2,4096,3]
    float* out_feat = out + (size_t)BB * SS * 3;         // [2,128,4096]
    float* out_sidx = out_feat + (size_t)BB * 128 * SS;  // [2,4096]

    char* ws = (char*)d_ws;
    float4* pts4    = (float4*)(ws + WS_PTS4);
    ushort* feat_nc = (ushort*)(ws + WS_FEAT);
    ushort* W1t     = (ushort*)(ws + WS_W1T);
    ushort* W2t     = (ushort*)(ws + WS_W2T);
    ushort* W3t     = (ushort*)(ws + WS_W3T);
    uint*   counts  = (uint*)(ws + WS_CNT);
    uint*   ccnt    = (uint*)(ws + WS_CCNT);
    uint*   wlc     = (uint*)(ws + WS_WLC);
    uint*   wl      = (uint*)(ws + WS_WL);
    float4* lpts    = (float4*)(ws + WS_LPTS);
    int*    cslot   = (int*)(ws + WS_CSLOT);

    hipMemsetAsync(counts, 0, MEMSET_B, stream);   // counts + ccnt + cursor
    prep_kernel<<<NBLK, 256, 0, stream>>>(
        xyz, feat, W1, W2, W3, pts4, feat_nc, W1t, W2t, W3t, out_xyz, out_sidx,
        counts, lpts, ccnt, cslot, wlc, wl);
    fused_kernel<<<2048, 256, 0, stream>>>(pts4, feat_nc, counts, lpts,
                                           ccnt, cslot, wlc, wl,
                                           W1t, W2t, W3t, b1, b2, b3, out_feat);
}

// Round 15
// 138.882 us; speedup vs baseline: 2.0731x; 2.0731x over previous
//
#include <hip/hip_runtime.h>

#define BB 2
#define NN 16384
#define CC 64
#define SS 4096
#define KK 32
#define R2 0.16f   // RADIUS^2

// spatial grid: cell = RADIUS, 24^3 cells covering [-4.8, 4.8] (clamped; the
// clamp is monotone so the 3x3x3 neighborhood remains a superset of the ball
// for ANY input magnitude — tail points just pile into edge cells)
#define GD   24
#define GC   (GD * GD * GD)       // 13824 cells per batch
#define CAPC 112                  // per-cell bucket capacity (center cell ~66)
#define CAP  512                  // per-wave hit-list capacity
#define CAPL (CAP / 64)           // 8 register chunks for selection
#define ADDRN 1152                // per-wave candidate-address capacity

typedef __bf16 bf16x8 __attribute__((ext_vector_type(8)));
typedef float  f32x4  __attribute__((ext_vector_type(4)));

#define MFMA(a, b, c) __builtin_amdgcn_mfma_f32_16x16x32_bf16((a), (b), (c), 0, 0, 0)

static __device__ __forceinline__ ushort f2bf(float f) {
    __bf16 h = (__bf16)f;
    return *(ushort*)&h;
}

static __device__ __forceinline__ int cellc(float x) {
    int i = (int)floorf(x * 2.5f + 12.0f);
    return i < 0 ? 0 : (i > GD - 1 ? GD - 1 : i);
}

// workspace section offsets (bytes), all 16B aligned
#define WS_PTS4   0          // pts4:    2*16384*16    =   524,288
#define WS_FEAT   524288     // feat_nc: 2*16384*64*2  = 4,194,304
#define WS_W1T    4718592    // 64*96*2   = 12,288
#define WS_W2T    4730880    // 64*64*2   =  8,192
#define WS_W3T    4739072    // 128*64*2  = 16,384
#define WS_CNT    4755456    // counts: 2*13824*4 = 110,592
#define WS_LPTS   4866048    // coord+id buckets: 2*13824*112*16 = 49,545,216
                             // (end 54,411,264; id packed in .w — no list[])

// prep index ranges (block-granular: T_SIDX = 328 blocks exactly)
#define T_PTS   (BB * NN)                  // 32768
#define T_W1    (T_PTS + 64 * 96)          // 38912
#define T_W2    (T_W1 + 64 * 64)           // 43008
#define T_W3    (T_W2 + 128 * 64)          // 51200
#define T_NXYZ  (T_W3 + BB * SS * 3)       // 75776
#define T_SIDX  (T_NXYZ + BB * SS)         // 83968 = 328*256
#define FEAT_B0 (T_SIDX / 256)             // 328: first feat-transpose block
#define NBLK    (FEAT_B0 + BB * (NN / 32)) // 328 + 1024 = 1352 blocks

// ---------------------------------------------------------------------------
// prep: pts4=(x,y,z,|x|^2) + coordinate+id-carrying per-cell bucket insert;
// bf16 weight transposes; coalesced new_xyz copy; samp_idx; feat [B][C][N]
// fp32 -> [B][N][C] bf16 via LDS-tiled transpose (blocks >= FEAT_B0). One
// wide launch. (Exact R8/R13 structure — the session-best total.)
// ---------------------------------------------------------------------------
__global__ __launch_bounds__(256) void prep_kernel(
        const float* __restrict__ xyz, const float* __restrict__ feat,
        const float* __restrict__ W1, const float* __restrict__ W2,
        const float* __restrict__ W3,
        float4* __restrict__ pts4, ushort* __restrict__ feat_nc,
        ushort* __restrict__ W1t, ushort* __restrict__ W2t,
        ushort* __restrict__ W3t,
        float* __restrict__ out_xyz, float* __restrict__ out_sidx,
        uint* __restrict__ counts, float4* __restrict__ lpts) {
    if (blockIdx.x >= FEAT_B0) {
        // ---- LDS-tiled feat transpose: one 64ch x 32pt tile per block ----
        __shared__ float tile[64][33];                 // +1 pad
        const int g = blockIdx.x - FEAT_B0;            // 0..1023
        const int b = g >> 9, n0 = (g & 511) << 5;
        const int t = threadIdx.x;
        const float* fb = feat + (size_t)b * CC * NN + n0;
        #pragma unroll
        for (int cc = 0; cc < 8; ++cc) {
            const int c = cc * 8 + (t >> 5);
            tile[c][t & 31] = fb[(size_t)c * NN + (t & 31)];
        }
        __syncthreads();
        const int p = t >> 3, c8 = t & 7;
        uint u[4];
        #pragma unroll
        for (int q = 0; q < 4; ++q) {
            u[q] = (uint)f2bf(tile[c8 * 8 + 2 * q][p]) |
                   ((uint)f2bf(tile[c8 * 8 + 2 * q + 1][p]) << 16);
        }
        *(uint4*)(feat_nc + ((size_t)b * NN + n0 + p) * 64 + c8 * 8) =
            make_uint4(u[0], u[1], u[2], u[3]);
        return;
    }
    const int t = blockIdx.x * 256 + threadIdx.x;
    if (t < T_PTS) {
        const float* p = xyz + (size_t)t * 3;
        const float x = p[0], y = p[1], z = p[2];
        pts4[t] = make_float4(x, y, z, x * x + y * y + z * z);
        const int cell = (cellc(z) * GD + cellc(y)) * GD + cellc(x);
        const int b = t >> 14, n = t & (NN - 1);
        const uint rank = atomicAdd(&counts[(size_t)b * GC + cell], 1u);
        if (rank < CAPC) {
            const size_t slot = ((size_t)b * GC + cell) * CAPC + rank;
            lpts[slot] = make_float4(x, y, z, __int_as_float(n));
        }
    } else if (t < T_W1) {
        const int i = t - T_PTS;
        const int n = i / 96, k = i - n * 96;
        float v = 0.0f;
        if (k < 64) v = W1[(3 + k) * 64 + n];
        else if (k < 67) v = W1[(k - 64) * 64 + n];
        W1t[n * 96 + k] = f2bf(v);
    } else if (t < T_W2) {
        const int i = t - T_W1;
        const int n = i >> 6, k = i & 63;
        W2t[n * 64 + k] = f2bf(W2[k * 64 + n]);
    } else if (t < T_W3) {
        const int i = t - T_W2;
        const int n = i >> 6, k = i & 63;
        W3t[n * 64 + k] = f2bf(W3[k * 128 + n]);
    } else if (t < T_NXYZ) {
        const int i = t - T_W3;              // new_xyz = xyz[:, :SS] copy
        const int b = i / (SS * 3), j = i - b * (SS * 3);
        out_xyz[i] = xyz[(size_t)b * NN * 3 + j];
    } else if (t < T_SIDX) {
        const int i = t - T_NXYZ;
        out_sidx[i] = (float)(i & (SS - 1));
    }
}

// ---------------------------------------------------------------------------
// fused: one wave = one centroid, 4-wave blocks (R8 structure). Ball query:
// per-axis-factorized exact cell pruning; candidate addresses materialized
// ONCE into LDS (R12); chunk-4 pipelined candidate loop (R13). Selection
// (ballot-popcount 32-smallest), gather, MLP, maxpool-in-tails, coalesced
// float2 epilogue — the session-best measured configuration (138.7us).
// R14's cell-grouped restructure regressed 4x (scattered 4-B epilogue ->
// 221MB RMW write amplification across non-coherent XCD L2s) — reverted.
// LDS layout per wave (6656B): addrL[1152] ints | hit[512] ints.
// ---------------------------------------------------------------------------
__global__ __launch_bounds__(256, 2) void fused_kernel(
        const float4* __restrict__ pts4, const ushort* __restrict__ feat_nc,
        const uint* __restrict__ counts, const float4* __restrict__ lpts,
        const ushort* __restrict__ W1t, const ushort* __restrict__ W2t,
        const ushort* __restrict__ W3t,
        const float* __restrict__ b1, const float* __restrict__ b2,
        const float* __restrict__ b3, float* __restrict__ out_feat) {
    const int w = threadIdx.x >> 6, lane = threadIdx.x & 63;
    const int quad = lane >> 4, mrow = lane & 15;
    const int m = lane & 31, half = lane >> 5;

    __shared__ __align__(16) ushort ldsA[4][32 * 104];   // addr|hits -> g -> h1 -> h2 (+tails)
    ushort* gbuf = ldsA[w];
    int* addrL = (int*)gbuf;                             // [0, 4608) bytes
    int* hit = (int*)(gbuf + 2304);                      // [4608, 6656) bytes

    const int xcd = blockIdx.x & 7;
    const int slot = blockIdx.x >> 3;              // 0..255
    const int b = xcd >> 2;
    const int s0 = ((xcd & 3) * 256 + slot) * 4;   // block's 4-s tile
    const int s = s0 + w;

    const float4* pb = pts4 + (size_t)b * NN;
    const ushort* fbase = feat_nc + (size_t)b * NN * 64;
    const unsigned long long ltmask = (1ull << lane) - 1ull;

    // ================= ball query via pruned cell buckets =================
    {
        const float4 c = pb[s];
        const int cx = cellc(c.x), cy = cellc(c.y), cz = cellc(c.z);
        const uint* cntb = counts + (size_t)b * GC;
        const float4* lptsb = lpts + (size_t)b * GC * CAPC;

        // per-axis squared distances to the 3 candidate cells (offsets -1,0,+1)
        // and validity; constant-indexed arrays (rule-#20 safe).
        float d2x[3], d2y[3], d2z[3];
        bool vx[3], vy[3], vz[3];
        #pragma unroll
        for (int o = 0; o < 3; ++o) {
            {
                const int X = cx + o - 1;
                vx[o] = ((unsigned)X < GD);
                const float lo = (X <= 0)      ? -1e30f : (X - 12) * 0.4f;
                const float hi = (X >= GD - 1) ?  1e30f : (X - 11) * 0.4f;
                const float d = fmaxf(fmaxf(lo - c.x, c.x - hi), 0.0f);
                d2x[o] = d * d;
            }
            {
                const int Y = cy + o - 1;
                vy[o] = ((unsigned)Y < GD);
                const float lo = (Y <= 0)      ? -1e30f : (Y - 12) * 0.4f;
                const float hi = (Y >= GD - 1) ?  1e30f : (Y - 11) * 0.4f;
                const float d = fmaxf(fmaxf(lo - c.y, c.y - hi), 0.0f);
                d2y[o] = d * d;
            }
            {
                const int Z = cz + o - 1;
                vz[o] = ((unsigned)Z < GD);
                const float lo = (Z <= 0)      ? -1e30f : (Z - 12) * 0.4f;
                const float hi = (Z >= GD - 1) ?  1e30f : (Z - 11) * 0.4f;
                const float d = fmaxf(fmaxf(lo - c.z, c.z - hi), 0.0f);
                d2z[o] = d * d;
            }
        }

        // preload the 27 cell counts (parallel issue; wave-uniform addresses)
        int cnE[27];
        #pragma unroll
        for (int e = 0; e < 27; ++e) {
            const int ez = e / 9, ey = (e / 3) % 3, ex = e % 3;
            const int ci = ((cz + ez - 1) * GD + (cy + ey - 1)) * GD + (cx + ex - 1);
            const bool ok = vx[ex] && vy[ey] && vz[ez];
            const bool reach = (d2x[ex] + d2y[ey] + d2z[ez]) < (R2 + 1e-3f);
            int cn = (ok && reach) ? (int)cntb[ok ? ci : 0] : 0;
            cnE[e] = cn < CAPC ? cn : CAPC;
        }

        // materialize the candidate address list into LDS (one-time cost;
        // replaces the per-candidate 27-way select in the hot loop)
        int tot = 0;
        #pragma unroll
        for (int e = 0; e < 27; ++e) {
            int cn = cnE[e];
            if (cn > ADDRN - tot) cn = ADDRN - tot;   // memory-safety clamp
            if (cn > 0) {                              // wave-uniform branch
                const int ez = e / 9, ey = (e / 3) % 3, ex = e % 3;
                const int base =
                    (((cz + ez - 1) * GD + (cy + ey - 1)) * GD + (cx + ex - 1)) * CAPC;
                if (lane < cn) addrL[tot + lane] = base + lane;
                if (cn > 64 && lane + 64 < cn) addrL[tot + 64 + lane] = base + 64 + lane;
                tot += cn;
            }
        }

        int cnt = 0;
        if (tot > 0) {
            // chunk-4 pipelined candidate loop: 4 independent gathers issued
            // back-to-back, then processed (one latency per 256 candidates)
            for (int g0 = 0; g0 < tot; g0 += 256) {
                float4 q[4];
                #pragma unroll
                for (int k = 0; k < 4; ++k) {
                    const int g = g0 + k * 64 + lane;
                    const int a = (g < tot) ? addrL[g] : addrL[0];
                    q[k] = lptsb[a];
                }
                #pragma unroll
                for (int k = 0; k < 4; ++k) {
                    const int g = g0 + k * 64;
                    if (g < tot) {                     // wave-uniform gate
                        const bool act = (g + lane) < tot;
                        const float4 pc = q[k];
                        const float pw = pc.x * pc.x + pc.y * pc.y + pc.z * pc.z;
                        const float d = c.w + pw -
                            2.0f * (c.x * pc.x + c.y * pc.y + c.z * pc.z);
                        const bool h = act && (d < R2);
                        const unsigned long long mk = __ballot(h);
                        if (h) {
                            const int pp = cnt + __popcll(mk & ltmask);
                            if (pp < CAP) hit[pp] = __float_as_int(pc.w);
                        }
                        cnt += (int)__popcll(mk);
                    }
                }
            }
        }

        // ---- keep the 32 smallest original indices (set-equivalent to the
        // reference "first nsample in index order"; maxpool ignores order) ----
        if (cnt > KK) {
            const int stored = cnt < CAP ? cnt : CAP;
            int v[CAPL];
            #pragma unroll
            for (int j = 0; j < CAPL; ++j) {
                if (j * 64 < stored) {             // chunk-gated preload
                    const int q = j * 64 + lane;
                    v[j] = (q < stored) ? hit[q] : 0x7fffffff;
                } else {
                    v[j] = 0x7fffffff;
                }
            }
            int lo = 0, hi = NN - 1;
            while (lo < hi) {                      // wave-uniform, <=14 iters
                const int mid = (lo + hi) >> 1;
                int cle = 0;
                #pragma unroll
                for (int j = 0; j < CAPL; ++j)
                    if (j * 64 < stored)           // wave-uniform chunk gate
                        cle += (int)__popcll(__ballot(v[j] <= mid));
                if (cle >= KK) hi = mid; else lo = mid + 1;
            }
            int pos = 0;                           // exactly KK selected (ids unique)
            #pragma unroll
            for (int j = 0; j < CAPL; ++j) {
                if (j * 64 < stored) {
                    const bool sel = v[j] <= lo;
                    const unsigned long long mk = __ballot(sel);
                    if (sel) hit[pos + __popcll(mk & ltmask)] = v[j];
                    pos += (int)__popcll(mk);
                }
            }
        } else if (lane < KK) {
            const int vv = (cnt == 0) ? 0 : ((lane < cnt) ? hit[lane] : hit[0]);
            hit[lane] = vv;
        }
    }

    // ================= gather: sid (LDS) -> rows -> LDS =================
    {
        const int sid = hit[m];                  // wave-private, program order
        const ushort* src = fbase + (size_t)sid * 64 + half * 32;
        ushort* dst = gbuf + m * 104 + half * 32;
        uint4 rows[4];
        #pragma unroll
        for (int i = 0; i < 4; ++i) rows[i] = *(const uint4*)(src + i * 8);
        const float4 p = pb[sid];
        const float4 cc = pb[s];
        #pragma unroll
        for (int i = 0; i < 4; ++i) *(uint4*)(dst + i * 8) = rows[i];
        if (half == 0) {
            bf16x8 rel = {(__bf16)(p.x - cc.x), (__bf16)(p.y - cc.y),
                          (__bf16)(p.z - cc.z), (__bf16)0.f,
                          (__bf16)0.f, (__bf16)0.f, (__bf16)0.f, (__bf16)0.f};
            *(bf16x8*)(gbuf + m * 104 + 64) = rel;
            *(uint4*)(gbuf + m * 104 + 88) = make_uint4(0, 0, 0, 0);
        } else {
            *(uint4*)(gbuf + m * 104 + 72) = make_uint4(0, 0, 0, 0);
            *(uint4*)(gbuf + m * 104 + 80) = make_uint4(0, 0, 0, 0);
        }
    }

    // ================= layer 1: [32x96]x[96x64] =================
    {
        f32x4 acc[2][4];
        #pragma unroll
        for (int nt = 0; nt < 4; ++nt) {
            const float bv = b1[nt * 16 + mrow];
            acc[0][nt] = (f32x4){bv, bv, bv, bv};
            acc[1][nt] = acc[0][nt];
        }
        #pragma unroll
        for (int ks = 0; ks < 3; ++ks) {
            const bf16x8 a0 = *(const bf16x8*)(gbuf + mrow * 104 + ks * 32 + quad * 8);
            const bf16x8 a1 = *(const bf16x8*)(gbuf + (16 + mrow) * 104 + ks * 32 + quad * 8);
            #pragma unroll
            for (int nt = 0; nt < 4; ++nt) {
                const bf16x8 wf = *(const bf16x8*)(W1t + (nt * 16 + mrow) * 96 + ks * 32 + quad * 8);
                acc[0][nt] = MFMA(a0, wf, acc[0][nt]);
                acc[1][nt] = MFMA(a1, wf, acc[1][nt]);
            }
        }
        #pragma unroll
        for (int mt = 0; mt < 2; ++mt)
            #pragma unroll
            for (int nt = 0; nt < 4; ++nt)
                #pragma unroll
                for (int r = 0; r < 4; ++r)
                    gbuf[(mt * 16 + quad * 4 + r) * 104 + nt * 16 + mrow] =
                        f2bf(fmaxf(acc[mt][nt][r], 0.0f));
    }

    // ================= layer 2: [32x64]x[64x64] =================
    {
        f32x4 acc[2][4];
        #pragma unroll
        for (int nt = 0; nt < 4; ++nt) {
            const float bv = b2[nt * 16 + mrow];
            acc[0][nt] = (f32x4){bv, bv, bv, bv};
            acc[1][nt] = acc[0][nt];
        }
        #pragma unroll
        for (int ks = 0; ks < 2; ++ks) {
            const bf16x8 a0 = *(const bf16x8*)(gbuf + mrow * 104 + ks * 32 + quad * 8);
            const bf16x8 a1 = *(const bf16x8*)(gbuf + (16 + mrow) * 104 + ks * 32 + quad * 8);
            #pragma unroll
            for (int nt = 0; nt < 4; ++nt) {
                const bf16x8 wf = *(const bf16x8*)(W2t + (nt * 16 + mrow) * 64 + ks * 32 + quad * 8);
                acc[0][nt] = MFMA(a0, wf, acc[0][nt]);
                acc[1][nt] = MFMA(a1, wf, acc[1][nt]);
            }
        }
        #pragma unroll
        for (int mt = 0; mt < 2; ++mt)
            #pragma unroll
            for (int nt = 0; nt < 4; ++nt)
                #pragma unroll
                for (int r = 0; r < 4; ++r)
                    gbuf[(mt * 16 + quad * 4 + r) * 104 + nt * 16 + mrow] =
                        f2bf(fmaxf(acc[mt][nt][r], 0.0f));
    }

    // ============ layer 3: [32x64]x[64x128] two n-halves + maxpool ==========
    // maxpool results go to the free 16B tail of each gbuf row (bytes 192-207;
    // MFMA reads touch only cols 0-63).
    #pragma unroll
    for (int nh = 0; nh < 2; ++nh) {
        f32x4 acc[2][4];
        #pragma unroll
        for (int ntl = 0; ntl < 4; ++ntl) {
            const float bv = b3[(nh * 4 + ntl) * 16 + mrow];
            acc[0][ntl] = (f32x4){bv, bv, bv, bv};
            acc[1][ntl] = acc[0][ntl];
        }
        #pragma unroll
        for (int ks = 0; ks < 2; ++ks) {
            const bf16x8 a0 = *(const bf16x8*)(gbuf + mrow * 104 + ks * 32 + quad * 8);
            const bf16x8 a1 = *(const bf16x8*)(gbuf + (16 + mrow) * 104 + ks * 32 + quad * 8);
            #pragma unroll
            for (int ntl = 0; ntl < 4; ++ntl) {
                const bf16x8 wf = *(const bf16x8*)(
                    W3t + ((nh * 4 + ntl) * 16 + mrow) * 64 + ks * 32 + quad * 8);
                acc[0][ntl] = MFMA(a0, wf, acc[0][ntl]);
                acc[1][ntl] = MFMA(a1, wf, acc[1][ntl]);
            }
        }
        #pragma unroll
        for (int ntl = 0; ntl < 4; ++ntl) {
            const f32x4 v0 = acc[0][ntl], v1 = acc[1][ntl];
            float mx = fmaxf(fmaxf(v0[0], v0[1]), fmaxf(v0[2], v0[3]));
            mx = fmaxf(mx, fmaxf(fmaxf(v1[0], v1[1]), fmaxf(v1[2], v1[3])));
            mx = fmaxf(mx, __shfl_xor(mx, 16));
            mx = fmaxf(mx, __shfl_xor(mx, 32));
            mx = fmaxf(mx, 0.0f);
            if (quad == 0) {
                const int ch = (nh * 4 + ntl) * 16 + mrow;
                *(float*)((char*)gbuf + (ch >> 2) * 208 + 192 + (ch & 3) * 4) = mx;
            }
        }
    }
    __syncthreads();

    // ---- epilogue: 128 ch x 4 s, float2 per thread (reads gbuf tails) ----
    {
        const int ch = threadIdx.x & 127;
        const int hf = threadIdx.x >> 7;           // 0/1
        const int tb = (ch >> 2) * 208 + 192 + (ch & 3) * 4;
        const float v0 = *(const float*)((const char*)ldsA[hf * 2] + tb);
        const float v1 = *(const float*)((const char*)ldsA[hf * 2 + 1] + tb);
        float* dst = out_feat + ((size_t)b * 128 + ch) * SS + s0 + hf * 2;
        *(float2*)dst = make_float2(v0, v1);
    }
}

// ---------------------------------------------------------------------------
extern "C" void kernel_launch(void* const* d_in, const int* in_sizes, int n_in,
                              void* d_out, int out_size, void* d_ws, size_t ws_size,
                              hipStream_t stream) {
    const float* xyz  = (const float*)d_in[0];
    const float* feat = (const float*)d_in[1];
    const float* W1   = (const float*)d_in[2];
    const float* b1   = (const float*)d_in[3];
    const float* W2   = (const float*)d_in[4];
    const float* b2   = (const float*)d_in[5];
    const float* W3   = (const float*)d_in[6];
    const float* b3   = (const float*)d_in[7];

    float* out      = (float*)d_out;
    float* out_xyz  = out;                               // [2,4096,3]
    float* out_feat = out + (size_t)BB * SS * 3;         // [2,128,4096]
    float* out_sidx = out_feat + (size_t)BB * 128 * SS;  // [2,4096]

    char* ws = (char*)d_ws;
    float4* pts4    = (float4*)(ws + WS_PTS4);
    ushort* feat_nc = (ushort*)(ws + WS_FEAT);
    ushort* W1t     = (ushort*)(ws + WS_W1T);
    ushort* W2t     = (ushort*)(ws + WS_W2T);
    ushort* W3t     = (ushort*)(ws + WS_W3T);
    uint*   counts  = (uint*)(ws + WS_CNT);
    float4* lpts    = (float4*)(ws + WS_LPTS);

    hipMemsetAsync(counts, 0, (size_t)BB * GC * 4, stream);
    prep_kernel<<<NBLK, 256, 0, stream>>>(
        xyz, feat, W1, W2, W3, pts4, feat_nc, W1t, W2t, W3t, out_xyz, out_sidx,
        counts, lpts);
    fused_kernel<<<BB * SS / 4, 256, 0, stream>>>(pts4, feat_nc, counts, lpts,
                                                  W1t, W2t, W3t, b1, b2, b3,
                                                  out_feat);
}